// Round 1
// baseline (370.870 us; speedup 1.0000x reference)
//
#include <hip/hip_runtime.h>
#include <stdint.h>

#define N_DET 8192
#define E_DIM 64

__device__ __forceinline__ unsigned fmap(float x) {
    unsigned b = __float_as_uint(x);
    return (b & 0x80000000u) ? ~b : (b | 0x80000000u);
}

// ---------------- K1: embed both detection sets ----------------
// One wave (64 lanes) per detection row; lane = embedding channel.
__global__ __launch_bounds__(256) void k_embed(
    const float* __restrict__ dt, const float* __restrict__ dt1,
    const float* __restrict__ W1, const float* __restrict__ b1,
    const float* __restrict__ W2, const float* __restrict__ b2,
    float* __restrict__ eout)
{
    int wave = (blockIdx.x * 256 + threadIdx.x) >> 6;
    int lane = threadIdx.x & 63;
    if (wave >= 2 * N_DET) return;
    const float* src = (wave < N_DET) ? (dt + (size_t)wave * 4)
                                      : (dt1 + (size_t)(wave - N_DET) * 4);
    float x0 = src[0], x1 = src[1], x2 = src[2], x3 = src[3];
    float h = b1[lane];
    h = fmaf(x0, W1[lane],        h);
    h = fmaf(x1, W1[64  + lane],  h);
    h = fmaf(x2, W1[128 + lane],  h);
    h = fmaf(x3, W1[192 + lane],  h);
    h = fmaxf(h, 0.0f);
    float e = b2[lane];
    #pragma unroll
    for (int k = 0; k < 64; ++k) {
        float hk = __shfl(h, k, 64);
        e = fmaf(hk, W2[k * 64 + lane], e);
    }
    float s = e * e;
    #pragma unroll
    for (int m = 32; m >= 1; m >>= 1) s += __shfl_xor(s, m, 64);
    float n = sqrtf(s);
    n = fmaxf(n, 1e-12f);
    eout[(size_t)wave * 64 + lane] = e / n;
}

// ---------------- K2: sim = e_t @ e_t1^T ----------------
// Thread owns one column (its e_t1 row in 64 VGPRs); loops 128 rows.
// A-row loads are wave-uniform (scalar-loadable); stores coalesced.
__global__ __launch_bounds__(256) void k_sim(
    const float* __restrict__ et, const float* __restrict__ et1,
    float* __restrict__ sim)
{
    int col = blockIdx.x * 256 + threadIdx.x;
    const float4* bp = (const float4*)(et1 + (size_t)col * 64);
    float4 b[16];
    #pragma unroll
    for (int q = 0; q < 16; ++q) b[q] = bp[q];
    int row0 = blockIdx.y * 128;
    for (int r = 0; r < 128; ++r) {
        int row = row0 + r;
        const float4* ap = (const float4*)(et + (size_t)row * 64);
        float a0 = 0.f, a1 = 0.f, a2 = 0.f, a3 = 0.f;
        #pragma unroll
        for (int q = 0; q < 16; ++q) {
            float4 a = ap[q];
            a0 = fmaf(a.x, b[q].x, a0);
            a1 = fmaf(a.y, b[q].y, a1);
            a2 = fmaf(a.z, b[q].z, a2);
            a3 = fmaf(a.w, b[q].w, a3);
        }
        sim[(size_t)row * N_DET + col] = (a0 + a1) + (a2 + a3);
    }
}

// ---------------- K3: per-row max + argmax (first occurrence) ----------------
__global__ __launch_bounds__(256) void k_rowmax(
    const float* __restrict__ sim, unsigned long long* __restrict__ rowkey)
{
    int row = blockIdx.x;
    int t = threadIdx.x;
    const float4* rp = (const float4*)(sim + (size_t)row * N_DET);
    float best = -3.0e38f;
    int bcol = 0x7fffffff;
    #pragma unroll
    for (int q = 0; q < 8; ++q) {
        float4 v = rp[q * 256 + t];
        int c0 = (q * 256 + t) * 4;
        if (v.x > best) { best = v.x; bcol = c0;     }
        if (v.y > best) { best = v.y; bcol = c0 + 1; }
        if (v.z > best) { best = v.z; bcol = c0 + 2; }
        if (v.w > best) { best = v.w; bcol = c0 + 3; }
    }
    #pragma unroll
    for (int m = 32; m >= 1; m >>= 1) {
        float os = __shfl_xor(best, m, 64);
        int   oc = __shfl_xor(bcol, m, 64);
        if (os > best || (os == best && oc < bcol)) { best = os; bcol = oc; }
    }
    __shared__ float ss[4];
    __shared__ int   sc[4];
    int wid = t >> 6;
    if ((t & 63) == 0) { ss[wid] = best; sc[wid] = bcol; }
    __syncthreads();
    if (t == 0) {
        #pragma unroll
        for (int w = 1; w < 4; ++w) {
            if (ss[w] > best || (ss[w] == best && sc[w] < bcol)) { best = ss[w]; bcol = sc[w]; }
        }
        rowkey[row] = ((unsigned long long)fmap(best) << 32) | (unsigned)bcol;
    }
}

// ---------------- K4/K5: greedy matching via per-column winner ----------------
__global__ void k_init(unsigned long long* __restrict__ winner) {
    int i = blockIdx.x * 256 + threadIdx.x;
    if (i < N_DET) winner[i] = 0ull;
}

__global__ void k_claim(const unsigned long long* __restrict__ rowkey,
                        unsigned long long* __restrict__ winner, unsigned uthr) {
    int i = blockIdx.x * 256 + threadIdx.x;
    if (i >= N_DET) return;
    unsigned long long k = rowkey[i];
    unsigned u   = (unsigned)(k >> 32);
    unsigned col = (unsigned)k;
    if (u > uthr) {
        unsigned long long claim = ((unsigned long long)u << 32) | (~(unsigned)i);
        atomicMax(&winner[col], claim);
    }
}

__global__ void k_match(const unsigned long long* __restrict__ rowkey,
                        const unsigned long long* __restrict__ winner,
                        float* __restrict__ out, unsigned uthr) {
    int i = blockIdx.x * 256 + threadIdx.x;
    if (i >= N_DET) return;
    unsigned long long k = rowkey[i];
    unsigned u   = (unsigned)(k >> 32);
    unsigned col = (unsigned)k;
    float m = -1.0f;
    if (u > uthr) {
        unsigned long long claim = ((unsigned long long)u << 32) | (~(unsigned)i);
        if (winner[col] == claim) m = (float)col;
    }
    out[i] = m;
}

extern "C" void kernel_launch(void* const* d_in, const int* in_sizes, int n_in,
                              void* d_out, int out_size, void* d_ws, size_t ws_size,
                              hipStream_t stream) {
    const float* dt  = (const float*)d_in[0];
    const float* dt1 = (const float*)d_in[1];
    const float* W1  = (const float*)d_in[2];
    const float* b1  = (const float*)d_in[3];
    const float* W2  = (const float*)d_in[4];
    const float* b2  = (const float*)d_in[5];

    float* out     = (float*)d_out;        // [0:8192) matches (as float), then sim row-major
    float* sim     = out + N_DET;

    char* ws = (char*)d_ws;
    float* et  = (float*)ws;                                 // 8192*64 f32
    float* et1 = et + (size_t)N_DET * E_DIM;                 // 8192*64 f32 (contiguous)
    unsigned long long* rowkey = (unsigned long long*)(ws + 2ull * N_DET * E_DIM * 4); // 8192 u64
    unsigned long long* winner = rowkey + N_DET;                                        // 8192 u64

    // 0.3f is positive: ordered map = bits | 0x80000000
    unsigned uthr;
    { union { float f; unsigned u; } c; c.f = 0.3f; uthr = c.u | 0x80000000u; }

    k_embed<<<(2 * N_DET) / 4, 256, 0, stream>>>(dt, dt1, W1, b1, W2, b2, et);
    k_init<<<N_DET / 256, 256, 0, stream>>>(winner);

    dim3 g2(N_DET / 256, N_DET / 128);
    k_sim<<<g2, 256, 0, stream>>>(et, et1, sim);

    k_rowmax<<<N_DET, 256, 0, stream>>>(sim, rowkey);
    k_claim<<<N_DET / 256, 256, 0, stream>>>(rowkey, winner, uthr);
    k_match<<<N_DET / 256, 256, 0, stream>>>(rowkey, winner, out, uthr);
}

// Round 2
// 157.934 us; speedup vs baseline: 2.3483x; 2.3483x over previous
//
#include <hip/hip_runtime.h>
#include <stdint.h>

#define N_DET 8192
#define E_DIM 64
#define LSTR 132   // padded LDS row stride (words) for k-major tiles

__device__ __forceinline__ unsigned fmap(float x) {
    unsigned b = __float_as_uint(x);
    return (b & 0x80000000u) ? ~b : (b | 0x80000000u);
}
__device__ __forceinline__ unsigned long long umax64(unsigned long long a, unsigned long long b) {
    return a > b ? a : b;
}

// ---------------- K1: embed both detection sets ----------------
// One wave (64 lanes) per detection row; lane = embedding channel.
__global__ __launch_bounds__(256) void k_embed(
    const float* __restrict__ dt, const float* __restrict__ dt1,
    const float* __restrict__ W1, const float* __restrict__ b1,
    const float* __restrict__ W2, const float* __restrict__ b2,
    float* __restrict__ eout)
{
    int wave = (blockIdx.x * 256 + threadIdx.x) >> 6;
    int lane = threadIdx.x & 63;
    if (wave >= 2 * N_DET) return;
    const float* src = (wave < N_DET) ? (dt + (size_t)wave * 4)
                                      : (dt1 + (size_t)(wave - N_DET) * 4);
    float x0 = src[0], x1 = src[1], x2 = src[2], x3 = src[3];
    float h = b1[lane];
    h = fmaf(x0, W1[lane],        h);
    h = fmaf(x1, W1[64  + lane],  h);
    h = fmaf(x2, W1[128 + lane],  h);
    h = fmaf(x3, W1[192 + lane],  h);
    h = fmaxf(h, 0.0f);
    float e = b2[lane];
    #pragma unroll
    for (int k = 0; k < 64; ++k) {
        float hk = __shfl(h, k, 64);
        e = fmaf(hk, W2[k * 64 + lane], e);
    }
    float s = e * e;
    #pragma unroll
    for (int m = 32; m >= 1; m >>= 1) s += __shfl_xor(s, m, 64);
    float n = sqrtf(s);
    n = fmaxf(n, 1e-12f);
    eout[(size_t)wave * 64 + lane] = e / n;
}

// ---------------- K2: fused sim = e_t @ e_t1^T  +  per-row max/argmax ----------------
// 128x128 tile per block, K=64 whole. 256 threads, 8x8 outputs each.
// LDS k-major, stride 132 words: frag reads are ds_read_b128, 2-way aliasing (free).
__global__ __launch_bounds__(256, 2) void k_sim_fused(
    const float* __restrict__ et, const float* __restrict__ et1,
    float* __restrict__ sim, unsigned long long* __restrict__ rowkey)
{
    __shared__ float As[64 * LSTR];
    __shared__ float Bs[64 * LSTR];
    const int tid = threadIdx.x;
    const int bx = blockIdx.x, by = blockIdx.y;

    // stage: global row-major -> LDS k-major (transpose in the write)
    {
        const float4* ag = (const float4*)(et  + (size_t)by * 128 * 64);
        const float4* bg = (const float4*)(et1 + (size_t)bx * 128 * 64);
        #pragma unroll
        for (int i = 0; i < 8; ++i) {
            int f = tid + i * 256;          // 0..2047
            int m = f >> 4;                 // row within tile 0..127
            int k = (f & 15) * 4;           // k base 0..60
            float4 va = ag[f];
            As[(k + 0) * LSTR + m] = va.x;
            As[(k + 1) * LSTR + m] = va.y;
            As[(k + 2) * LSTR + m] = va.z;
            As[(k + 3) * LSTR + m] = va.w;
            float4 vb = bg[f];
            Bs[(k + 0) * LSTR + m] = vb.x;
            Bs[(k + 1) * LSTR + m] = vb.y;
            Bs[(k + 2) * LSTR + m] = vb.z;
            Bs[(k + 3) * LSTR + m] = vb.w;
        }
    }
    __syncthreads();

    const int tx = tid & 15;   // column group
    const int ty = tid >> 4;   // row group
    float acc[8][8];
    #pragma unroll
    for (int i = 0; i < 8; ++i)
        #pragma unroll
        for (int j = 0; j < 8; ++j) acc[i][j] = 0.0f;

    const float4* As4 = (const float4*)As;   // 33 float4 per k-row
    const float4* Bs4 = (const float4*)Bs;

    #pragma unroll 2
    for (int k = 0; k < 64; ++k) {
        const int base = k * 33;
        float4 a0 = As4[base + ty];
        float4 a1 = As4[base + 16 + ty];
        float4 b0 = Bs4[base + tx];
        float4 b1 = Bs4[base + 16 + tx];
        float a[8] = {a0.x, a0.y, a0.z, a0.w, a1.x, a1.y, a1.z, a1.w};
        float b[8] = {b0.x, b0.y, b0.z, b0.w, b1.x, b1.y, b1.z, b1.w};
        #pragma unroll
        for (int i = 0; i < 8; ++i)
            #pragma unroll
            for (int j = 0; j < 8; ++j)
                acc[i][j] = fmaf(a[i], b[j], acc[i][j]);
    }

    // epilogue: coalesced stores + fused row max/argmax
    const int cbase = bx * 128;
    #pragma unroll
    for (int i = 0; i < 8; ++i) {
        int mrow = (i < 4) ? (ty * 4 + i) : (64 + ty * 4 + (i - 4));
        size_t rg = (size_t)by * 128 + mrow;
        float4* sp = (float4*)(sim + rg * N_DET + cbase);
        sp[tx]      = make_float4(acc[i][0], acc[i][1], acc[i][2], acc[i][3]);
        sp[16 + tx] = make_float4(acc[i][4], acc[i][5], acc[i][6], acc[i][7]);

        unsigned long long key = 0ull;
        #pragma unroll
        for (int j = 0; j < 8; ++j) {
            int col = cbase + ((j < 4) ? (tx * 4 + j) : (64 + tx * 4 + (j - 4)));
            unsigned long long kk =
                ((unsigned long long)fmap(acc[i][j]) << 32) | (unsigned)(~col);
            key = umax64(key, kk);
        }
        #pragma unroll
        for (int m = 1; m < 16; m <<= 1)
            key = umax64(key, __shfl_xor(key, m, 64));
        if (tx == 0) atomicMax(&rowkey[rg], key);
    }
}

// ---------------- K0: zero rowkey+winner (contiguous 2*N u64) ----------------
__global__ void k_init(unsigned long long* __restrict__ p) {
    p[blockIdx.x * 256 + threadIdx.x] = 0ull;
}

// ---------------- K3/K4: greedy matching via per-column winner ----------------
__global__ void k_claim(const unsigned long long* __restrict__ rowkey,
                        unsigned long long* __restrict__ winner, unsigned uthr) {
    int i = blockIdx.x * 256 + threadIdx.x;
    if (i >= N_DET) return;
    unsigned long long k = rowkey[i];
    unsigned u = (unsigned)(k >> 32);
    if (u > uthr) {
        unsigned col = ~(unsigned)k;                // 0..8191
        unsigned long long claim = ((unsigned long long)u << 32) | (~(unsigned)i);
        atomicMax(&winner[col], claim);
    }
}

__global__ void k_match(const unsigned long long* __restrict__ rowkey,
                        const unsigned long long* __restrict__ winner,
                        float* __restrict__ out, unsigned uthr) {
    int i = blockIdx.x * 256 + threadIdx.x;
    if (i >= N_DET) return;
    unsigned long long k = rowkey[i];
    unsigned u = (unsigned)(k >> 32);
    float m = -1.0f;
    if (u > uthr) {
        unsigned col = ~(unsigned)k;
        unsigned long long claim = ((unsigned long long)u << 32) | (~(unsigned)i);
        if (winner[col] == claim) m = (float)col;
    }
    out[i] = m;
}

extern "C" void kernel_launch(void* const* d_in, const int* in_sizes, int n_in,
                              void* d_out, int out_size, void* d_ws, size_t ws_size,
                              hipStream_t stream) {
    const float* dt  = (const float*)d_in[0];
    const float* dt1 = (const float*)d_in[1];
    const float* W1  = (const float*)d_in[2];
    const float* b1  = (const float*)d_in[3];
    const float* W2  = (const float*)d_in[4];
    const float* b2  = (const float*)d_in[5];

    float* out = (float*)d_out;            // [0:8192) matches (float), then sim row-major
    float* sim = out + N_DET;

    char* ws = (char*)d_ws;
    float* et  = (float*)ws;                                  // 8192*64 f32
    float* et1 = et + (size_t)N_DET * E_DIM;                  // 8192*64 f32
    unsigned long long* rowkey = (unsigned long long*)(ws + 2ull * N_DET * E_DIM * 4);
    unsigned long long* winner = rowkey + N_DET;              // contiguous after rowkey

    unsigned uthr;
    { union { float f; unsigned u; } c; c.f = 0.3f; uthr = c.u | 0x80000000u; }

    k_embed<<<(2 * N_DET) / 4, 256, 0, stream>>>(dt, dt1, W1, b1, W2, b2, et);
    k_init<<<(2 * N_DET) / 256, 256, 0, stream>>>(rowkey);    // zeros rowkey + winner

    dim3 g2(N_DET / 128, N_DET / 128);
    k_sim_fused<<<g2, 256, 0, stream>>>(et, et1, sim, rowkey);

    k_claim<<<N_DET / 256, 256, 0, stream>>>(rowkey, winner, uthr);
    k_match<<<N_DET / 256, 256, 0, stream>>>(rowkey, winner, out, uthr);
}